// Round 1
// baseline (861.166 us; speedup 1.0000x reference)
//
#include <hip/hip_runtime.h>
#include <math.h>

#define Bc 256
#define Tc 1024
#define RNN_DIMc 1024
#define ENC_DIMc 512
#define ATT_DIMc 128
#define NFILTc 32
#define KSIZEc 31
#define PADc 15

__device__ __forceinline__ float fast_tanh(float x) {
    x = fminf(15.f, fmaxf(-15.f, x));
    float z = __expf(2.f * x);
    return (z - 1.f) / (z + 1.f);
}

__device__ __forceinline__ float wave_reduce_max(float x) {
#pragma unroll
    for (int off = 32; off > 0; off >>= 1) x = fmaxf(x, __shfl_xor(x, off, 64));
    return x;
}

__device__ __forceinline__ float wave_reduce_sum(float x) {
#pragma unroll
    for (int off = 32; off > 0; off >>= 1) x += __shfl_xor(x, off, 64);
    return x;
}

// ---------------- Kernel 1: pq[b][a] = sum_r W_q[a][r] * query[b][r] ----------------
__global__ __launch_bounds__(128) void qproj_k(const float* __restrict__ query,
                                               const float* __restrict__ W_q,
                                               float* __restrict__ pq) {
    const int b = blockIdx.x;
    __shared__ float q[RNN_DIMc];
    for (int i = threadIdx.x; i < RNN_DIMc; i += 128) q[i] = query[b * RNN_DIMc + i];
    __syncthreads();
    const float* w = W_q + (size_t)threadIdx.x * RNN_DIMc;
    float acc = 0.f;
#pragma unroll 4
    for (int r = 0; r < RNN_DIMc; r += 4) {
        float4 wv = *(const float4*)(w + r);
        acc = fmaf(wv.x, q[r + 0], acc);
        acc = fmaf(wv.y, q[r + 1], acc);
        acc = fmaf(wv.z, q[r + 2], acc);
        acc = fmaf(wv.w, q[r + 3], acc);
    }
    pq[b * ATT_DIMc + threadIdx.x] = acc;
}

// ---------------- Kernel 2: energies[b][t] (conv -> dense -> tanh -> v.h), masked ----------------
__global__ __launch_bounds__(256) void energies_k(
    const float* __restrict__ attn_w, const float* __restrict__ cum_w,
    const float* __restrict__ pm, const float* __restrict__ pq,
    const float* __restrict__ conv_w, const float* __restrict__ W_loc,
    const float* __restrict__ v_w, const float* __restrict__ v_b,
    const int* __restrict__ lens, float* __restrict__ energies) {
    const int b = blockIdx.x >> 2;
    const int t0 = (blockIdx.x & 3) * 256;
    const int t = t0 + threadIdx.x;

    __shared__ float s_a[256 + 2 * PADc];
    __shared__ float s_c[256 + 2 * PADc];
    for (int i = threadIdx.x; i < 256 + 2 * PADc; i += 256) {
        int tt = t0 - PADc + i;
        bool ok = (tt >= 0) && (tt < Tc);
        s_a[i] = ok ? attn_w[b * Tc + tt] : 0.f;
        s_c[i] = ok ? cum_w[b * Tc + tt] : 0.f;
    }
    __syncthreads();

    // conv window in registers
    float wa[KSIZEc], wcm[KSIZEc];
#pragma unroll
    for (int k = 0; k < KSIZEc; ++k) {
        wa[k] = s_a[threadIdx.x + k];
        wcm[k] = s_c[threadIdx.x + k];
    }

    // location conv: loc[f] = sum_k cw[f][0][k]*attn[t+k-P] + cw[f][1][k]*cum[t+k-P]
    float loc[NFILTc];
#pragma unroll
    for (int f = 0; f < NFILTc; ++f) {
        const float* cw = conv_w + f * (2 * KSIZEc);
        float a0 = 0.f, a1 = 0.f;
#pragma unroll
        for (int k = 0; k < KSIZEc; ++k) {
            a0 = fmaf(cw[k], wa[k], a0);
            a1 = fmaf(cw[KSIZEc + k], wcm[k], a1);
        }
        loc[f] = a0 + a1;
    }

    // dense (32->128) fused with tanh + v-dot
    const float* pmrow = pm + ((size_t)(b * Tc + t)) * ATT_DIMc;
    const float* pqr = pq + b * ATT_DIMc;
    float e = 0.f;
#pragma unroll 2
    for (int a = 0; a < ATT_DIMc; a += 4) {
        float4 pmv = *(const float4*)(pmrow + a);
        const float* wl = W_loc + a * NFILTc;
        float pl0 = 0.f, pl1 = 0.f, pl2 = 0.f, pl3 = 0.f;
#pragma unroll
        for (int f = 0; f < NFILTc; ++f) {
            float lf = loc[f];
            pl0 = fmaf(wl[f], lf, pl0);
            pl1 = fmaf(wl[NFILTc + f], lf, pl1);
            pl2 = fmaf(wl[2 * NFILTc + f], lf, pl2);
            pl3 = fmaf(wl[3 * NFILTc + f], lf, pl3);
        }
        e = fmaf(v_w[a + 0], fast_tanh(pqr[a + 0] + pl0 + pmv.x), e);
        e = fmaf(v_w[a + 1], fast_tanh(pqr[a + 1] + pl1 + pmv.y), e);
        e = fmaf(v_w[a + 2], fast_tanh(pqr[a + 2] + pl2 + pmv.z), e);
        e = fmaf(v_w[a + 3], fast_tanh(pqr[a + 3] + pl3 + pmv.w), e);
    }
    e += v_b[0];
    if (t >= lens[b]) e = -INFINITY;
    energies[b * Tc + t] = e;
}

// ---------------- Kernel 3: softmax over t, write new_attn and new_cum ----------------
__global__ __launch_bounds__(256) void softmax_k(const float* __restrict__ energies,
                                                 const float* __restrict__ cum_in,
                                                 float* __restrict__ out_attn,
                                                 float* __restrict__ out_cum) {
    const int b = blockIdx.x;
    const float* e = energies + b * Tc;
    float ev[4];
    float m = -INFINITY;
#pragma unroll
    for (int i = 0; i < 4; ++i) {
        ev[i] = e[threadIdx.x + 256 * i];
        m = fmaxf(m, ev[i]);
    }
    m = wave_reduce_max(m);
    __shared__ float redm[4];
    __shared__ float reds[4];
    const int wid = threadIdx.x >> 6;
    if ((threadIdx.x & 63) == 0) redm[wid] = m;
    __syncthreads();
    m = fmaxf(fmaxf(redm[0], redm[1]), fmaxf(redm[2], redm[3]));

    float p[4];
    float s = 0.f;
#pragma unroll
    for (int i = 0; i < 4; ++i) {
        p[i] = __expf(ev[i] - m);  // exp(-inf - m) == 0 for masked positions
        s += p[i];
    }
    s = wave_reduce_sum(s);
    if ((threadIdx.x & 63) == 0) reds[wid] = s;
    __syncthreads();
    s = reds[0] + reds[1] + reds[2] + reds[3];
    float inv = 1.f / s;
#pragma unroll
    for (int i = 0; i < 4; ++i) {
        int t = threadIdx.x + 256 * i;
        float na = p[i] * inv;
        out_attn[b * Tc + t] = na;
        out_cum[b * Tc + t] = cum_in[b * Tc + t] + na;
    }
}

// ---------------- Kernel 4: partial context over t-segments ----------------
__global__ __launch_bounds__(512) void ctx_partial_k(const float* __restrict__ attn,
                                                     const float* __restrict__ memory,
                                                     float* __restrict__ partial) {
    const int b = blockIdx.x >> 2;
    const int seg = blockIdx.x & 3;
    const int e = threadIdx.x;  // 0..511
    const float* ar = attn + b * Tc + seg * 256;
    const float* mr = memory + ((size_t)(b * Tc + seg * 256)) * ENC_DIMc + e;
    float acc = 0.f;
#pragma unroll 4
    for (int tt = 0; tt < 256; ++tt) {
        acc = fmaf(ar[tt], mr[(size_t)tt * ENC_DIMc], acc);
    }
    partial[(size_t)blockIdx.x * ENC_DIMc + e] = acc;
}

// ---------------- Kernel 5: reduce 4 partials -> context ----------------
__global__ __launch_bounds__(256) void ctx_reduce_k(const float* __restrict__ partial,
                                                    float* __restrict__ ctx) {
    const int idx = blockIdx.x * 256 + threadIdx.x;  // < B*ENC_DIM
    const int b = idx >> 9;
    const int e = idx & 511;
    float s = partial[(size_t)(b * 4 + 0) * ENC_DIMc + e] +
              partial[(size_t)(b * 4 + 1) * ENC_DIMc + e] +
              partial[(size_t)(b * 4 + 2) * ENC_DIMc + e] +
              partial[(size_t)(b * 4 + 3) * ENC_DIMc + e];
    ctx[idx] = s;
}

extern "C" void kernel_launch(void* const* d_in, const int* in_sizes, int n_in,
                              void* d_out, int out_size, void* d_ws, size_t ws_size,
                              hipStream_t stream) {
    const float* query  = (const float*)d_in[0];
    const float* memory = (const float*)d_in[1];
    const float* pm     = (const float*)d_in[2];
    const float* attn_w = (const float*)d_in[3];
    const float* cum_w  = (const float*)d_in[4];
    const int*   lens   = (const int*)d_in[5];
    const float* conv_w = (const float*)d_in[6];
    const float* W_loc  = (const float*)d_in[7];
    const float* W_q    = (const float*)d_in[8];
    const float* v_w    = (const float*)d_in[9];
    const float* v_b    = (const float*)d_in[10];

    float* out      = (float*)d_out;
    float* ctx      = out;                         // B*ENC_DIM
    float* out_attn = out + Bc * ENC_DIMc;         // B*T
    float* out_cum  = out + Bc * ENC_DIMc + Bc * Tc;

    // ws layout (aliased across kernel lifetimes; 2 MiB total):
    //   phase A: pq @ 0 (32768 floats), energies @ 32768 (262144 floats)
    //   phase B: partial @ 0 (524288 floats) — pq/energies dead by then
    float* pq       = (float*)d_ws;
    float* energies = pq + Bc * ATT_DIMc;
    float* partial  = (float*)d_ws;

    qproj_k<<<Bc, 128, 0, stream>>>(query, W_q, pq);
    energies_k<<<Bc * 4, 256, 0, stream>>>(attn_w, cum_w, pm, pq, conv_w, W_loc, v_w, v_b,
                                           lens, energies);
    softmax_k<<<Bc, 256, 0, stream>>>(energies, cum_w, out_attn, out_cum);
    ctx_partial_k<<<Bc * 4, 512, 0, stream>>>(out_attn, memory, partial);
    ctx_reduce_k<<<(Bc * ENC_DIMc) / 256, 256, 0, stream>>>(partial, ctx);
}

// Round 2
// 829.186 us; speedup vs baseline: 1.0386x; 1.0386x over previous
//
#include <hip/hip_runtime.h>
#include <math.h>

#define Bc 256
#define Tc 1024
#define RNN_DIMc 1024
#define ENC_DIMc 512
#define ATT_DIMc 128
#define NFILTc 32
#define KSIZEc 31
#define PADc 15

__device__ __forceinline__ float fast_tanh(float x) {
    x = fminf(15.f, fmaxf(-15.f, x));
    float z = __expf(2.f * x);
    return (z - 1.f) / (z + 1.f);
}

__device__ __forceinline__ float wave_reduce_max(float x) {
#pragma unroll
    for (int off = 32; off > 0; off >>= 1) x = fmaxf(x, __shfl_xor(x, off, 64));
    return x;
}

__device__ __forceinline__ float wave_reduce_sum(float x) {
#pragma unroll
    for (int off = 32; off > 0; off >>= 1) x += __shfl_xor(x, off, 64);
    return x;
}

// One block per batch row b. 1024 threads.
// Phases: [0] stage q + attn/cum windows  [1] qproj  [2] conv+dense+tanh energies
//         [3] block softmax               [4] context reduction over memory[b]
__global__ __launch_bounds__(1024) void lsa_fused(
    const float* __restrict__ query, const float* __restrict__ memory,
    const float* __restrict__ pm, const float* __restrict__ attn_w,
    const float* __restrict__ cum_w, const int* __restrict__ lens,
    const float* __restrict__ conv_w, const float* __restrict__ W_loc,
    const float* __restrict__ W_q, const float* __restrict__ v_w,
    const float* __restrict__ v_b, float* __restrict__ ctx,
    float* __restrict__ out_attn, float* __restrict__ out_cum) {
    const int b = blockIdx.x;
    const int tid = threadIdx.x;

    __shared__ float s_q[RNN_DIMc];              // 4 KiB
    __shared__ float s_pq[ATT_DIMc];             // 0.5 KiB
    __shared__ float s_win0[Tc + 2 * PADc];      // 4.2 KiB  attn window
    __shared__ float s_win1[Tc + 2 * PADc];      // 4.2 KiB  cum window
    __shared__ float s_attn[Tc];                 // 4 KiB
    __shared__ float s_redm[16];
    __shared__ float s_reds[16];
    __shared__ float s_scratch[8][ENC_DIMc];     // 16 KiB (qproj partials / ctx partials)

    // ---------------- Phase 0: stage query + padded windows ----------------
    if (tid < RNN_DIMc) s_q[tid] = query[b * RNN_DIMc + tid];
    for (int i = tid; i < Tc + 2 * PADc; i += 1024) {
        int tt = i - PADc;
        bool ok = (tt >= 0) && (tt < Tc);
        s_win0[i] = ok ? attn_w[b * Tc + tt] : 0.f;
        s_win1[i] = ok ? cum_w[b * Tc + tt] : 0.f;
    }
    __syncthreads();

    // ---------------- Phase 1: qproj (8 threads per output a) ----------------
    {
        const int a = tid >> 3;   // 0..127
        const int c = tid & 7;    // 0..7
        const float* w = W_q + (size_t)a * RNN_DIMc + c * 128;
        const float* qq = s_q + c * 128;
        float acc = 0.f;
#pragma unroll
        for (int j = 0; j < 128; j += 4) {
            float4 wv = *(const float4*)(w + j);
            acc = fmaf(wv.x, qq[j + 0], acc);
            acc = fmaf(wv.y, qq[j + 1], acc);
            acc = fmaf(wv.z, qq[j + 2], acc);
            acc = fmaf(wv.w, qq[j + 3], acc);
        }
        ((float*)s_scratch)[a * 8 + c] = acc;
    }
    __syncthreads();
    if (tid < ATT_DIMc) {
        const float* p = (const float*)s_scratch + tid * 8;
        s_pq[tid] = p[0] + p[1] + p[2] + p[3] + p[4] + p[5] + p[6] + p[7];
    }
    __syncthreads();

    // ---------------- Phase 2: energies e[t] (conv -> dense -> tanh -> v.h) ----------------
    const int t = tid;
    float e;
    {
        // location conv, k-outer / f-inner: only loc[32] live (low VGPR)
        float loc[NFILTc];
#pragma unroll
        for (int f = 0; f < NFILTc; ++f) loc[f] = 0.f;
        for (int k = 0; k < KSIZEc; ++k) {
            const float wa = s_win0[t + k];
            const float wc = s_win1[t + k];
#pragma unroll
            for (int f = 0; f < NFILTc; ++f) {
                loc[f] = fmaf(conv_w[f * (2 * KSIZEc) + k], wa, loc[f]);
                loc[f] = fmaf(conv_w[f * (2 * KSIZEc) + KSIZEc + k], wc, loc[f]);
            }
        }

        // dense (32->128) fused with tanh + v-dot
        const float* pmrow = pm + ((size_t)(b * Tc + t)) * ATT_DIMc;
        e = 0.f;
#pragma unroll 2
        for (int a = 0; a < ATT_DIMc; a += 4) {
            float4 pmv = *(const float4*)(pmrow + a);
            const float* wl = W_loc + a * NFILTc;
            float pl0 = 0.f, pl1 = 0.f, pl2 = 0.f, pl3 = 0.f;
#pragma unroll
            for (int f = 0; f < NFILTc; ++f) {
                float lf = loc[f];
                pl0 = fmaf(wl[f], lf, pl0);
                pl1 = fmaf(wl[NFILTc + f], lf, pl1);
                pl2 = fmaf(wl[2 * NFILTc + f], lf, pl2);
                pl3 = fmaf(wl[3 * NFILTc + f], lf, pl3);
            }
            e = fmaf(v_w[a + 0], fast_tanh(s_pq[a + 0] + pl0 + pmv.x), e);
            e = fmaf(v_w[a + 1], fast_tanh(s_pq[a + 1] + pl1 + pmv.y), e);
            e = fmaf(v_w[a + 2], fast_tanh(s_pq[a + 2] + pl2 + pmv.z), e);
            e = fmaf(v_w[a + 3], fast_tanh(s_pq[a + 3] + pl3 + pmv.w), e);
        }
        e += v_b[0];
        if (t >= lens[b]) e = -INFINITY;
    }

    // ---------------- Phase 3: block softmax over t ----------------
    {
        float m = wave_reduce_max(e);
        if ((tid & 63) == 0) s_redm[tid >> 6] = m;
        __syncthreads();
        float bm = s_redm[0];
#pragma unroll
        for (int j = 1; j < 16; ++j) bm = fmaxf(bm, s_redm[j]);

        float p = __expf(e - bm);  // masked: exp(-inf) == 0
        float s = wave_reduce_sum(p);
        if ((tid & 63) == 0) s_reds[tid >> 6] = s;
        __syncthreads();
        float tot = 0.f;
#pragma unroll
        for (int j = 0; j < 16; ++j) tot += s_reds[j];
        float na = p * (1.f / tot);

        out_attn[b * Tc + t] = na;
        out_cum[b * Tc + t] = s_win1[t + PADc] + na;  // cum[t] already staged in LDS
        s_attn[t] = na;
    }
    __syncthreads();

    // ---------------- Phase 4: context = sum_t attn[t] * memory[b,t,:] ----------------
    {
        const int tr = tid >> 7;          // 0..7 : t-residue class
        const int e4 = (tid & 127) * 4;   // 0..508 : float4 column
        const float* mb = memory + (size_t)b * Tc * ENC_DIMc;
        float4 acc = make_float4(0.f, 0.f, 0.f, 0.f);
#pragma unroll 4
        for (int tt = tr; tt < Tc; tt += 8) {
            const float w = s_attn[tt];  // wave-uniform broadcast
            const float4 mv = *(const float4*)(mb + (size_t)tt * ENC_DIMc + e4);
            acc.x = fmaf(w, mv.x, acc.x);
            acc.y = fmaf(w, mv.y, acc.y);
            acc.z = fmaf(w, mv.z, acc.z);
            acc.w = fmaf(w, mv.w, acc.w);
        }
        *(float4*)&s_scratch[tr][e4] = acc;
    }
    __syncthreads();
    if (tid < ENC_DIMc) {
        float s = 0.f;
#pragma unroll
        for (int j = 0; j < 8; ++j) s += s_scratch[j][tid];
        ctx[b * ENC_DIMc + tid] = s;
    }
}

extern "C" void kernel_launch(void* const* d_in, const int* in_sizes, int n_in,
                              void* d_out, int out_size, void* d_ws, size_t ws_size,
                              hipStream_t stream) {
    const float* query  = (const float*)d_in[0];
    const float* memory = (const float*)d_in[1];
    const float* pm     = (const float*)d_in[2];
    const float* attn_w = (const float*)d_in[3];
    const float* cum_w  = (const float*)d_in[4];
    const int*   lens   = (const int*)d_in[5];
    const float* conv_w = (const float*)d_in[6];
    const float* W_loc  = (const float*)d_in[7];
    const float* W_q    = (const float*)d_in[8];
    const float* v_w    = (const float*)d_in[9];
    const float* v_b    = (const float*)d_in[10];

    float* out      = (float*)d_out;
    float* ctx      = out;                              // B*ENC_DIM
    float* out_attn = out + Bc * ENC_DIMc;              // B*T
    float* out_cum  = out + Bc * ENC_DIMc + Bc * Tc;    // B*T

    lsa_fused<<<Bc, 1024, 0, stream>>>(query, memory, pm, attn_w, cum_w, lens,
                                       conv_w, W_loc, W_q, v_w, v_b,
                                       ctx, out_attn, out_cum);
}

// Round 3
// 818.288 us; speedup vs baseline: 1.0524x; 1.0133x over previous
//
#include <hip/hip_runtime.h>
#include <math.h>

#define Bc 256
#define Tc 1024
#define RNN_DIMc 1024
#define ENC_DIMc 512
#define ATT_DIMc 128
#define NFILTc 32
#define KSIZEc 31
#define PADc 15

typedef float f4v __attribute__((ext_vector_type(4)));

__device__ __forceinline__ float fast_tanh(float x) {
    x = fminf(15.f, fmaxf(-15.f, x));
    float z = __expf(2.f * x);
    return (z - 1.f) / (z + 1.f);
}

__device__ __forceinline__ float wave_reduce_max(float x) {
#pragma unroll
    for (int off = 32; off > 0; off >>= 1) x = fmaxf(x, __shfl_xor(x, off, 64));
    return x;
}

__device__ __forceinline__ float wave_reduce_sum(float x) {
#pragma unroll
    for (int off = 32; off > 0; off >>= 1) x += __shfl_xor(x, off, 64);
    return x;
}

// ---------------- Kernel 1: pq[b][a] = W_q[a,:] . query[b,:] ----------------
__global__ __launch_bounds__(128) void qproj_k(const float* __restrict__ query,
                                               const float* __restrict__ W_q,
                                               float* __restrict__ pq) {
    const int b = blockIdx.x;
    __shared__ float q[RNN_DIMc];
    for (int i = threadIdx.x; i < RNN_DIMc; i += 128) q[i] = query[b * RNN_DIMc + i];
    __syncthreads();
    const float* w = W_q + (size_t)threadIdx.x * RNN_DIMc;
    float acc = 0.f;
#pragma unroll 4
    for (int r = 0; r < RNN_DIMc; r += 4) {
        float4 wv = *(const float4*)(w + r);
        acc = fmaf(wv.x, q[r + 0], acc);
        acc = fmaf(wv.y, q[r + 1], acc);
        acc = fmaf(wv.z, q[r + 2], acc);
        acc = fmaf(wv.w, q[r + 3], acc);
    }
    pq[b * ATT_DIMc + threadIdx.x] = acc;
}

// ---------------- Kernel 2 (fused): energies -> softmax -> context, one block per b ----------------
__global__ __launch_bounds__(1024) void lsa_fused(
    const float* __restrict__ memory, const float* __restrict__ pm,
    const float* __restrict__ attn_w, const float* __restrict__ cum_w,
    const int* __restrict__ lens, const float* __restrict__ conv_w,
    const float* __restrict__ W_loc, const float* __restrict__ pq_g,
    const float* __restrict__ v_w, const float* __restrict__ v_b,
    float* __restrict__ ctx, float* __restrict__ out_attn, float* __restrict__ out_cum) {
    const int b = blockIdx.x;
    const int tid = threadIdx.x;
    const int len = lens[b];

    __shared__ float s_pq[ATT_DIMc];             // 0.5 KiB
    __shared__ float s_win0[Tc + 2 * PADc];      // 4.2 KiB  attn window
    __shared__ float s_win1[Tc + 2 * PADc];      // 4.2 KiB  cum window
    __shared__ float s_attn[Tc];                 // 4 KiB
    __shared__ float s_redm[16];
    __shared__ float s_reds[16];
    __shared__ float s_scratch[8][ENC_DIMc];     // 16 KiB (ctx partials)

    // ---------------- Phase 0: stage pq + padded windows ----------------
    if (tid < ATT_DIMc) s_pq[tid] = pq_g[b * ATT_DIMc + tid];
    for (int i = tid; i < Tc + 2 * PADc; i += 1024) {
        int tt = i - PADc;
        bool ok = (tt >= 0) && (tt < Tc);
        s_win0[i] = ok ? attn_w[b * Tc + tt] : 0.f;
        s_win1[i] = ok ? cum_w[b * Tc + tt] : 0.f;
    }
    __syncthreads();

    // ---------------- Phase 2: energies e[t] (conv -> dense -> tanh -> v.h), masked skip ----------------
    const int t = tid;
    float e = -INFINITY;
    if (t < len) {
        // location conv, k-outer / f-inner: only loc[32] live (low VGPR)
        float loc[NFILTc];
#pragma unroll
        for (int f = 0; f < NFILTc; ++f) loc[f] = 0.f;
        for (int k = 0; k < KSIZEc; ++k) {
            const float wa = s_win0[t + k];
            const float wc = s_win1[t + k];
#pragma unroll
            for (int f = 0; f < NFILTc; ++f) {
                loc[f] = fmaf(conv_w[f * (2 * KSIZEc) + k], wa, loc[f]);
                loc[f] = fmaf(conv_w[f * (2 * KSIZEc) + KSIZEc + k], wc, loc[f]);
            }
        }

        // dense (32->128) fused with tanh + v-dot
        const float* pmrow = pm + ((size_t)(b * Tc + t)) * ATT_DIMc;
        float acc = 0.f;
#pragma unroll 2
        for (int a = 0; a < ATT_DIMc; a += 4) {
            const f4v pmv = __builtin_nontemporal_load((const f4v*)(pmrow + a));
            const float* wl = W_loc + a * NFILTc;
            float pl0 = 0.f, pl1 = 0.f, pl2 = 0.f, pl3 = 0.f;
#pragma unroll
            for (int f = 0; f < NFILTc; ++f) {
                float lf = loc[f];
                pl0 = fmaf(wl[f], lf, pl0);
                pl1 = fmaf(wl[NFILTc + f], lf, pl1);
                pl2 = fmaf(wl[2 * NFILTc + f], lf, pl2);
                pl3 = fmaf(wl[3 * NFILTc + f], lf, pl3);
            }
            acc = fmaf(v_w[a + 0], fast_tanh(s_pq[a + 0] + pl0 + pmv.x), acc);
            acc = fmaf(v_w[a + 1], fast_tanh(s_pq[a + 1] + pl1 + pmv.y), acc);
            acc = fmaf(v_w[a + 2], fast_tanh(s_pq[a + 2] + pl2 + pmv.z), acc);
            acc = fmaf(v_w[a + 3], fast_tanh(s_pq[a + 3] + pl3 + pmv.w), acc);
        }
        e = acc + v_b[0];
    }

    // ---------------- Phase 3: block softmax over t ----------------
    {
        float m = wave_reduce_max(e);
        if ((tid & 63) == 0) s_redm[tid >> 6] = m;
        __syncthreads();
        float bm = s_redm[0];
#pragma unroll
        for (int j = 1; j < 16; ++j) bm = fmaxf(bm, s_redm[j]);

        float p = __expf(e - bm);  // masked: exp(-inf) == 0
        float s = wave_reduce_sum(p);
        if ((tid & 63) == 0) s_reds[tid >> 6] = s;
        __syncthreads();
        float tot = 0.f;
#pragma unroll
        for (int j = 0; j < 16; ++j) tot += s_reds[j];
        float na = p * (1.f / tot);

        out_attn[b * Tc + t] = na;
        out_cum[b * Tc + t] = s_win1[t + PADc] + na;  // cum[t] staged in LDS
        s_attn[t] = na;
    }
    __syncthreads();

    // ---------------- Phase 4: context = sum_{t<len} attn[t] * memory[b,t,:] ----------------
    {
        const int tr = tid >> 7;          // 0..7 : t-residue class
        const int e4 = (tid & 127) * 4;   // 0..508 : float4 column
        const float* mb = memory + (size_t)b * Tc * ENC_DIMc;
        f4v acc = {0.f, 0.f, 0.f, 0.f};
#pragma unroll 4
        for (int tt = tr; tt < len; tt += 8) {   // attn[t>=len] == 0 exactly: skip
            const float w = s_attn[tt];  // wave-uniform broadcast
            const f4v mv = __builtin_nontemporal_load((const f4v*)(mb + (size_t)tt * ENC_DIMc + e4));
            acc.x = fmaf(w, mv.x, acc.x);
            acc.y = fmaf(w, mv.y, acc.y);
            acc.z = fmaf(w, mv.z, acc.z);
            acc.w = fmaf(w, mv.w, acc.w);
        }
        *(f4v*)&s_scratch[tr][e4] = acc;
    }
    __syncthreads();
    if (tid < ENC_DIMc) {
        float s = 0.f;
#pragma unroll
        for (int j = 0; j < 8; ++j) s += s_scratch[j][tid];
        ctx[b * ENC_DIMc + tid] = s;
    }
}

extern "C" void kernel_launch(void* const* d_in, const int* in_sizes, int n_in,
                              void* d_out, int out_size, void* d_ws, size_t ws_size,
                              hipStream_t stream) {
    const float* query  = (const float*)d_in[0];
    const float* memory = (const float*)d_in[1];
    const float* pm     = (const float*)d_in[2];
    const float* attn_w = (const float*)d_in[3];
    const float* cum_w  = (const float*)d_in[4];
    const int*   lens   = (const int*)d_in[5];
    const float* conv_w = (const float*)d_in[6];
    const float* W_loc  = (const float*)d_in[7];
    const float* W_q    = (const float*)d_in[8];
    const float* v_w    = (const float*)d_in[9];
    const float* v_b    = (const float*)d_in[10];

    float* out      = (float*)d_out;
    float* ctx      = out;                              // B*ENC_DIM
    float* out_attn = out + Bc * ENC_DIMc;              // B*T
    float* out_cum  = out + Bc * ENC_DIMc + Bc * Tc;    // B*T

    float* pq = (float*)d_ws;   // B*ATT_DIM floats

    qproj_k<<<Bc, 128, 0, stream>>>(query, W_q, pq);
    lsa_fused<<<Bc, 1024, 0, stream>>>(memory, pm, attn_w, cum_w, lens,
                                       conv_w, W_loc, pq, v_w, v_b,
                                       ctx, out_attn, out_cum);
}